// Round 9
// baseline (321.115 us; speedup 1.0000x reference)
//
#include <hip/hip_runtime.h>
#include <hip/hip_bf16.h>

#define NN 16384
#define EE 128

typedef __attribute__((ext_vector_type(8))) short bf16x8;   // 8 bf16 = 4 VGPRs (MFMA A/B frag)
typedef __attribute__((ext_vector_type(4))) float f32x4;    // MFMA C/D frag
typedef __attribute__((ext_vector_type(4))) float f4;

static __device__ inline short f2bf(float f) {
    __hip_bfloat16 h = __float2bfloat16(f);
    return *reinterpret_cast<short*>(&h);
}

// ---------------------------------------------------------------------------
// pack_a: A [16384][128] fp32 -> Apk fragment-packed bf16 (mfma operand layout:
// lane&15 -> index, (lane>>4)*8+j -> k; feedable to either mfma slot).
// ---------------------------------------------------------------------------
__global__ __launch_bounds__(256) void pack_a(const float* __restrict__ A,
                                              bf16x8* __restrict__ out) {
    int lane = threadIdx.x & 63;
    int unit = blockIdx.x * 4 + (threadIdx.x >> 6);   // 0..4095
    int m16 = unit >> 2, ks = unit & 3;
    int row = m16 * 16 + (lane & 15);
    int k0  = ks * 32 + (lane >> 4) * 8;
    const float* src = A + (size_t)row * EE + k0;
    f4 v0 = *reinterpret_cast<const f4*>(src);
    f4 v1 = *reinterpret_cast<const f4*>(src + 4);
    bf16x8 r;
    r[0] = f2bf(v0[0]); r[1] = f2bf(v0[1]); r[2] = f2bf(v0[2]); r[3] = f2bf(v0[3]);
    r[4] = f2bf(v1[0]); r[5] = f2bf(v1[1]); r[6] = f2bf(v1[2]); r[7] = f2bf(v1[3]);
    out[(size_t)unit * 64 + lane] = r;
}

// ---------------------------------------------------------------------------
// pack_b: B [128][16384] fp32, W[128] -> Bpk = bf16(W[k]*B[k][n]), same layout.
// ---------------------------------------------------------------------------
__global__ __launch_bounds__(256) void pack_b(const float* __restrict__ B,
                                              const float* __restrict__ W,
                                              bf16x8* __restrict__ out) {
    int lane = threadIdx.x & 63;
    int unit = blockIdx.x * 4 + (threadIdx.x >> 6);   // 0..4095
    int n16 = unit >> 2, ks = unit & 3;
    int n  = n16 * 16 + (lane & 15);
    int k0 = ks * 32 + (lane >> 4) * 8;
    bf16x8 r;
#pragma unroll
    for (int j = 0; j < 8; ++j) {
        int k = k0 + j;
        r[j] = f2bf(W[k] * B[(size_t)k * NN + n]);
    }
    out[(size_t)unit * 64 + lane] = r;
}

// ---------------------------------------------------------------------------
// gemm_pk: "store-shaped" restructure of R8. Block tile 32x256, 4 waves
// side-by-side (each 32x64 via swapped-operand mfma, acc = 2x4 f4 = 32 VGPR).
// Epilogue: stage the WHOLE tile in one 32 KB LDS buffer -> ONE barrier per
// block (R8: 8), then 8 full 1 KB contiguous row-stores per thread-wave.
// Low VGPR + 32 KB LDS -> 5 blocks/CU (R8: 4) for store-latency hiding.
// ---------------------------------------------------------------------------
__global__ __launch_bounds__(256, 5) void gemm_pk(const bf16x8* __restrict__ Apk,
                                                  const bf16x8* __restrict__ Bpk,
                                                  float* __restrict__ C) {
    // XCD chunking, bm-fast. bm in [0,512) (32-row tiles), bn in [0,64)
    // (256-col tiles). Per-XCD: one 2048-row band, A panel 512 KB L2-hot.
    int bid = blockIdx.x;
    int xcd = bid & 7;
    int r   = bid >> 3;                 // 0..4095
    int bm  = xcd * 64 + (r & 63);      // bm-fast
    int bn  = r >> 6;

    int lane = threadIdx.x & 63;
    int wid  = threadIdx.x >> 6;        // wave 0..3 = column quarter
    int m16_0 = bm * 2;                 // 2 m16-frags (32 rows)
    int n16_0 = bn * 16 + wid * 4;      // 4 n16-frags (64 cols of this wave)

    f32x4 acc[2][4];
#pragma unroll
    for (int m = 0; m < 2; ++m)
#pragma unroll
        for (int n = 0; n < 4; ++n)
            acc[m][n] = (f32x4){0.f, 0.f, 0.f, 0.f};

#pragma unroll
    for (int ks = 0; ks < 4; ++ks) {
        bf16x8 a[2], b[4];
#pragma unroll
        for (int m = 0; m < 2; ++m)
            a[m] = Apk[(size_t)((m16_0 + m) * 4 + ks) * 64 + lane];
#pragma unroll
        for (int n = 0; n < 4; ++n)
            b[n] = Bpk[(size_t)((n16_0 + n) * 4 + ks) * 64 + lane];
#pragma unroll
        for (int m = 0; m < 2; ++m)
#pragma unroll
            for (int n = 0; n < 4; ++n)  // swapped operands (R4-verified math)
                acc[m][n] = __builtin_amdgcn_mfma_f32_16x16x32_bf16(b[n], a[m], acc[m][n], 0, 0, 0);
    }
    // thread owns: C row bm*32 + m*16 + (lane&15),
    //              cols bn*256 + wid*64 + n*16 + (lane>>4)*4 + {0..3}

    // ---- epilogue: whole-tile staging, ONE barrier, 1 KB row stores ----
    __shared__ float sb[32 * 256];               // 32 KB
    int rg  = lane >> 4;                          // 0..3
    int l15 = lane & 15;
    int swW = (l15 & 7) << 2;                     // row&7 == l15&7 for m*16 rows

#pragma unroll
    for (int m = 0; m < 2; ++m) {
        int row = m * 16 + l15;
#pragma unroll
        for (int n = 0; n < 4; ++n) {
            int colf = (wid * 64 + n * 16 + rg * 4) ^ swW;
            *reinterpret_cast<f4*>(&sb[row * 256 + colf]) = acc[m][n];
        }
    }
    __syncthreads();

    size_t growb = (size_t)bm * 32;
    int    gcolb = bn * 256;
#pragma unroll
    for (int i = 0; i < 8; ++i) {
        int rl   = i * 4 + wid;
        int colf = (lane * 4) ^ ((rl & 7) << 2);
        f4 v = *reinterpret_cast<const f4*>(&sb[rl * 256 + colf]);
        *reinterpret_cast<f4*>(&C[(growb + rl) * NN + gcolb + lane * 4]) = v;
    }
}

// ---------------------------------------------------------------------------
// Fallback (only if ws_size < 8 MB): plain fp32, correct but slow.
// ---------------------------------------------------------------------------
__global__ __launch_bounds__(64) void gemm_fb(const float* __restrict__ A,
                                              const float* __restrict__ B,
                                              const float* __restrict__ W,
                                              float* __restrict__ C) {
    int col = blockIdx.x * 64 + threadIdx.x;
    int row = blockIdx.y;
    float s = 0.f;
#pragma unroll 8
    for (int k = 0; k < EE; ++k)
        s = fmaf(A[(size_t)row * EE + k] * W[k], B[(size_t)k * NN + col], s);
    C[(size_t)row * NN + col] = s;
}

extern "C" void kernel_launch(void* const* d_in, const int* in_sizes, int n_in,
                              void* d_out, int out_size, void* d_ws, size_t ws_size,
                              hipStream_t stream) {
    const float* A = (const float*)d_in[0];   // DV2_H        [16384,128]
    const float* B = (const float*)d_in[1];   // invDE_HT_DV2 [128,16384]
    const float* W = (const float*)d_in[2];   // W            [128]
    float* C = (float*)d_out;                 // G            [16384,16384] fp32

    const size_t need = (size_t)2 * 4096 * 64 * sizeof(bf16x8);  // 8 MB
    if (ws_size >= need) {
        bf16x8* Apk = (bf16x8*)d_ws;
        bf16x8* Bpk = Apk + (size_t)4096 * 64;
        pack_a<<<1024, 256, 0, stream>>>(A, Apk);
        pack_b<<<1024, 256, 0, stream>>>(B, W, Bpk);
        gemm_pk<<<32768, 256, 0, stream>>>(Apk, Bpk, C);
    } else {
        dim3 g(NN / 64, NN);
        gemm_fb<<<g, 64, 0, stream>>>(A, B, W, C);
    }
}

// Round 10
// 312.249 us; speedup vs baseline: 1.0284x; 1.0284x over previous
//
#include <hip/hip_runtime.h>
#include <hip/hip_bf16.h>

#define NN 16384
#define EE 128

typedef __attribute__((ext_vector_type(8))) short bf16x8;   // 8 bf16 = 4 VGPRs (MFMA A/B frag)
typedef __attribute__((ext_vector_type(4))) float f32x4;    // MFMA C/D frag
typedef __attribute__((ext_vector_type(4))) float f4;

static __device__ inline short f2bf(float f) {
    __hip_bfloat16 h = __float2bfloat16(f);
    return *reinterpret_cast<short*>(&h);
}

// ---------------------------------------------------------------------------
// pack_a: A [16384][128] fp32 -> Apk fragment-packed bf16 (mfma operand layout:
// lane&15 -> index, (lane>>4)*8+j -> k; feedable to either mfma slot).
// ---------------------------------------------------------------------------
__global__ __launch_bounds__(256) void pack_a(const float* __restrict__ A,
                                              bf16x8* __restrict__ out) {
    int lane = threadIdx.x & 63;
    int unit = blockIdx.x * 4 + (threadIdx.x >> 6);   // 0..4095
    int m16 = unit >> 2, ks = unit & 3;
    int row = m16 * 16 + (lane & 15);
    int k0  = ks * 32 + (lane >> 4) * 8;
    const float* src = A + (size_t)row * EE + k0;
    f4 v0 = *reinterpret_cast<const f4*>(src);
    f4 v1 = *reinterpret_cast<const f4*>(src + 4);
    bf16x8 r;
    r[0] = f2bf(v0[0]); r[1] = f2bf(v0[1]); r[2] = f2bf(v0[2]); r[3] = f2bf(v0[3]);
    r[4] = f2bf(v1[0]); r[5] = f2bf(v1[1]); r[6] = f2bf(v1[2]); r[7] = f2bf(v1[3]);
    out[(size_t)unit * 64 + lane] = r;
}

// ---------------------------------------------------------------------------
// pack_b: B [128][16384] fp32, W[128] -> Bpk = bf16(W[k]*B[k][n]), same layout.
// ---------------------------------------------------------------------------
__global__ __launch_bounds__(256) void pack_b(const float* __restrict__ B,
                                              const float* __restrict__ W,
                                              bf16x8* __restrict__ out) {
    int lane = threadIdx.x & 63;
    int unit = blockIdx.x * 4 + (threadIdx.x >> 6);   // 0..4095
    int n16 = unit >> 2, ks = unit & 3;
    int n  = n16 * 16 + (lane & 15);
    int k0 = ks * 32 + (lane >> 4) * 8;
    bf16x8 r;
#pragma unroll
    for (int j = 0; j < 8; ++j) {
        int k = k0 + j;
        r[j] = f2bf(W[k] * B[(size_t)k * NN + n]);
    }
    out[(size_t)unit * 64 + lane] = r;
}

// ---------------------------------------------------------------------------
// gemm_pk: EXACT R8 structure (64x256 block tile, 4 waves side-by-side each
// 64x64 swapped-operand mfma, block-cooperative 16x256 LDS m-band staging,
// 1 KB contiguous row stores, occupancy 4) with ONE change: bn-FAST walk.
// XCD owns a 2048-row band (32 bm-tiles); concurrent blocks fill adjacent
// 1 KB column chunks of the SAME band -> dirty L2 evictions stream to DRAM
// in near-column order (page locality), instead of interleaving thousands
// of 64 KB-apart rows (bm-fast). Walk retest is only meaningful now that
// stores are 1 KB-contiguous (R5's bn-fast test used the scattered epilogue).
// ---------------------------------------------------------------------------
__global__ __launch_bounds__(256, 4) void gemm_pk(const bf16x8* __restrict__ Apk,
                                                  const bf16x8* __restrict__ Bpk,
                                                  float* __restrict__ C) {
    int bid   = blockIdx.x;
    int xcd   = bid & 7;
    int local = bid >> 3;               // 0..2047
    int bm    = xcd * 32 + (local >> 6);   // 32 bm-tiles (64 rows each) per XCD
    int bn    = local & 63;                // bn-fastest

    int lane = threadIdx.x & 63;
    int wid  = threadIdx.x >> 6;        // wave 0..3 = column quarter
    int m16_0 = bm * 4;                 // 4 m16-frags (64 rows)
    int n16_0 = bn * 16 + wid * 4;      // 4 n16-frags (64 cols of this wave)

    f32x4 acc[4][4];
#pragma unroll
    for (int m = 0; m < 4; ++m)
#pragma unroll
        for (int n = 0; n < 4; ++n)
            acc[m][n] = (f32x4){0.f, 0.f, 0.f, 0.f};

#pragma unroll
    for (int ks = 0; ks < 4; ++ks) {
        bf16x8 a[4], b[4];
#pragma unroll
        for (int m = 0; m < 4; ++m)
            a[m] = Apk[(size_t)((m16_0 + m) * 4 + ks) * 64 + lane];
#pragma unroll
        for (int n = 0; n < 4; ++n)
            b[n] = Bpk[(size_t)((n16_0 + n) * 4 + ks) * 64 + lane];
#pragma unroll
        for (int m = 0; m < 4; ++m)
#pragma unroll
            for (int n = 0; n < 4; ++n)  // swapped operands (R4-verified math)
                acc[m][n] = __builtin_amdgcn_mfma_f32_16x16x32_bf16(b[n], a[m], acc[m][n], 0, 0, 0);
    }
    // thread owns: C row bm*64 + m*16 + (lane&15),
    //              cols bn*256 + wid*64 + n*16 + (lane>>4)*4 + {0..3}

    // ---- epilogue: block-cooperative 16x256 m-band staging, 1KB row stores --
    __shared__ float sb[16 * 256];               // 16 KB
    int rg  = lane >> 4;                          // 0..3
    int l15 = lane & 15;
    size_t growb = (size_t)bm * 64;
    int    gcolb = bn * 256;

#pragma unroll
    for (int m = 0; m < 4; ++m) {
        // write: wave wid covers cols wid*64 + n*16 + rg*4, rows l15.
        int swW = (l15 & 7) << 2;
#pragma unroll
        for (int n = 0; n < 4; ++n) {
            int colf = (wid * 64 + n * 16 + rg * 4) ^ swW;
            *reinterpret_cast<f4*>(&sb[l15 * 256 + colf]) = acc[m][n];
        }
        __syncthreads();
        // read+store: wave wid handles rows i*4+wid; 64 lanes x 16B = one
        // full 1 KB contiguous row per instruction.
#pragma unroll
        for (int i = 0; i < 4; ++i) {
            int rl   = i * 4 + wid;
            int colf = (lane * 4) ^ ((rl & 7) << 2);
            f4 v = *reinterpret_cast<const f4*>(&sb[rl * 256 + colf]);
            *reinterpret_cast<f4*>(
                &C[(growb + m * 16 + rl) * NN + gcolb + lane * 4]) = v;
        }
        __syncthreads();   // before next band overwrites sb
    }
}

// ---------------------------------------------------------------------------
// Fallback (only if ws_size < 8 MB): plain fp32, correct but slow.
// ---------------------------------------------------------------------------
__global__ __launch_bounds__(64) void gemm_fb(const float* __restrict__ A,
                                              const float* __restrict__ B,
                                              const float* __restrict__ W,
                                              float* __restrict__ C) {
    int col = blockIdx.x * 64 + threadIdx.x;
    int row = blockIdx.y;
    float s = 0.f;
#pragma unroll 8
    for (int k = 0; k < EE; ++k)
        s = fmaf(A[(size_t)row * EE + k] * W[k], B[(size_t)k * NN + col], s);
    C[(size_t)row * NN + col] = s;
}

extern "C" void kernel_launch(void* const* d_in, const int* in_sizes, int n_in,
                              void* d_out, int out_size, void* d_ws, size_t ws_size,
                              hipStream_t stream) {
    const float* A = (const float*)d_in[0];   // DV2_H        [16384,128]
    const float* B = (const float*)d_in[1];   // invDE_HT_DV2 [128,16384]
    const float* W = (const float*)d_in[2];   // W            [128]
    float* C = (float*)d_out;                 // G            [16384,16384] fp32

    const size_t need = (size_t)2 * 4096 * 64 * sizeof(bf16x8);  // 8 MB
    if (ws_size >= need) {
        bf16x8* Apk = (bf16x8*)d_ws;
        bf16x8* Bpk = Apk + (size_t)4096 * 64;
        pack_a<<<1024, 256, 0, stream>>>(A, Apk);
        pack_b<<<1024, 256, 0, stream>>>(B, W, Bpk);
        gemm_pk<<<16384, 256, 0, stream>>>(Apk, Bpk, C);
    } else {
        dim3 g(NN / 64, NN);
        gemm_fb<<<g, 64, 0, stream>>>(A, B, W, C);
    }
}

// Round 11
// 280.680 us; speedup vs baseline: 1.1441x; 1.1125x over previous
//
#include <hip/hip_runtime.h>
#include <hip/hip_bf16.h>

#define NN 16384
#define EE 128

typedef __attribute__((ext_vector_type(8))) short bf16x8;   // 8 bf16 = 4 VGPRs (MFMA A/B frag)
typedef __attribute__((ext_vector_type(4))) float f32x4;    // MFMA C/D frag
typedef __attribute__((ext_vector_type(4))) float f4;

static __device__ inline short f2bf(float f) {
    __hip_bfloat16 h = __float2bfloat16(f);
    return *reinterpret_cast<short*>(&h);
}

// ---------------------------------------------------------------------------
// pack_a: A [16384][128] fp32 -> Apk fragment-packed bf16 (mfma operand layout:
// lane&15 -> index, (lane>>4)*8+j -> k; feedable to either mfma slot).
// ---------------------------------------------------------------------------
__global__ __launch_bounds__(256) void pack_a(const float* __restrict__ A,
                                              bf16x8* __restrict__ out) {
    int lane = threadIdx.x & 63;
    int unit = blockIdx.x * 4 + (threadIdx.x >> 6);   // 0..4095
    int m16 = unit >> 2, ks = unit & 3;
    int row = m16 * 16 + (lane & 15);
    int k0  = ks * 32 + (lane >> 4) * 8;
    const float* src = A + (size_t)row * EE + k0;
    f4 v0 = *reinterpret_cast<const f4*>(src);
    f4 v1 = *reinterpret_cast<const f4*>(src + 4);
    bf16x8 r;
    r[0] = f2bf(v0[0]); r[1] = f2bf(v0[1]); r[2] = f2bf(v0[2]); r[3] = f2bf(v0[3]);
    r[4] = f2bf(v1[0]); r[5] = f2bf(v1[1]); r[6] = f2bf(v1[2]); r[7] = f2bf(v1[3]);
    out[(size_t)unit * 64 + lane] = r;
}

// ---------------------------------------------------------------------------
// pack_b: B [128][16384] fp32, W[128] -> Bpk = bf16(W[k]*B[k][n]), same layout.
// ---------------------------------------------------------------------------
__global__ __launch_bounds__(256) void pack_b(const float* __restrict__ B,
                                              const float* __restrict__ W,
                                              bf16x8* __restrict__ out) {
    int lane = threadIdx.x & 63;
    int unit = blockIdx.x * 4 + (threadIdx.x >> 6);   // 0..4095
    int n16 = unit >> 2, ks = unit & 3;
    int n  = n16 * 16 + (lane & 15);
    int k0 = ks * 32 + (lane >> 4) * 8;
    bf16x8 r;
#pragma unroll
    for (int j = 0; j < 8; ++j) {
        int k = k0 + j;
        r[j] = f2bf(W[k] * B[(size_t)k * NN + n]);
    }
    out[(size_t)unit * 64 + lane] = r;
}

// ---------------------------------------------------------------------------
// gemm_pk: R8 scaled to a 64x512 block tile (8 waves side-by-side, each 64x64
// via swapped-operand mfma). Epilogue unchanged in structure: per 16-row
// m-band all waves stage into one 16x512 LDS buffer (32 KB, XOR-swizzled,
// all ds_*_b128), barrier, then each wave stores full 1 KB contiguous
// wave-stores, two back-to-back per 2 KB C row. vs R8: output rows are 2 KB
// contiguous (was 1 KB), blocks halve (8192 -> per-byte barrier/launch
// overhead halves), A-frags amortize over 2x output. bm-fast XCD walk (best
// measured R8/R10). Occupancy 2 blocks/CU = 16 waves/CU (same as R8).
// ---------------------------------------------------------------------------
__global__ __launch_bounds__(512, 4) void gemm_pk(const bf16x8* __restrict__ Apk,
                                                  const bf16x8* __restrict__ Bpk,
                                                  float* __restrict__ C) {
    // 8192 blocks = 256 bm (64-row) x 32 bn (512-col). XCD chunking, bm-fast.
    int bid   = blockIdx.x;
    int xcd   = bid & 7;
    int local = bid >> 3;                  // 0..1023
    int bm    = xcd * 32 + (local & 31);   // bm-fast
    int bn    = local >> 5;                // 0..31

    int lane = threadIdx.x & 63;
    int wid  = threadIdx.x >> 6;           // wave 0..7 = column eighth
    int m16_0 = bm * 4;                    // 4 m16-frags (64 rows)
    int n16_0 = bn * 32 + wid * 4;         // 4 n16-frags (64 cols of this wave)

    f32x4 acc[4][4];
#pragma unroll
    for (int m = 0; m < 4; ++m)
#pragma unroll
        for (int n = 0; n < 4; ++n)
            acc[m][n] = (f32x4){0.f, 0.f, 0.f, 0.f};

#pragma unroll
    for (int ks = 0; ks < 4; ++ks) {
        bf16x8 a[4], b[4];
#pragma unroll
        for (int m = 0; m < 4; ++m)
            a[m] = Apk[(size_t)((m16_0 + m) * 4 + ks) * 64 + lane];
#pragma unroll
        for (int n = 0; n < 4; ++n)
            b[n] = Bpk[(size_t)((n16_0 + n) * 4 + ks) * 64 + lane];
#pragma unroll
        for (int m = 0; m < 4; ++m)
#pragma unroll
            for (int n = 0; n < 4; ++n)  // swapped operands (R4-verified math)
                acc[m][n] = __builtin_amdgcn_mfma_f32_16x16x32_bf16(b[n], a[m], acc[m][n], 0, 0, 0);
    }
    // thread owns: C row bm*64 + m*16 + (lane&15),
    //              cols bn*512 + wid*64 + n*16 + (lane>>4)*4 + {0..3}

    // ---- epilogue: 16x512 m-band staging, 2 KB-contiguous row stores ----
    __shared__ float sb[16 * 512];               // 32 KB
    int rg  = lane >> 4;                          // 0..3
    int l15 = lane & 15;
    size_t growb = (size_t)bm * 64;
    int    gcolb = bn * 512;

#pragma unroll
    for (int m = 0; m < 4; ++m) {
        // write: wave wid covers cols wid*64 + n*16 + rg*4, rows l15.
        // swizzle on col bits [2:4] (16B-preserving): colf ^= (row&7)<<2.
        int swW = (l15 & 7) << 2;
#pragma unroll
        for (int n = 0; n < 4; ++n) {
            int colf = (wid * 64 + n * 16 + rg * 4) ^ swW;
            *reinterpret_cast<f4*>(&sb[l15 * 512 + colf]) = acc[m][n];
        }
        __syncthreads();
        // read+store: wave wid handles rows i*8+wid (i=0,1); per row two
        // back-to-back 1 KB wave-stores cover the 2 KB contiguous C row.
#pragma unroll
        for (int i = 0; i < 2; ++i) {
            int rl = i * 8 + wid;
            int sw = (rl & 7) << 2;
#pragma unroll
            for (int h = 0; h < 2; ++h) {
                int colf = (h * 256 + lane * 4) ^ sw;
                f4 v = *reinterpret_cast<const f4*>(&sb[rl * 512 + colf]);
                *reinterpret_cast<f4*>(
                    &C[(growb + m * 16 + rl) * NN + gcolb + h * 256 + lane * 4]) = v;
            }
        }
        __syncthreads();   // before next band overwrites sb
    }
}

// ---------------------------------------------------------------------------
// Fallback (only if ws_size < 8 MB): plain fp32, correct but slow.
// ---------------------------------------------------------------------------
__global__ __launch_bounds__(64) void gemm_fb(const float* __restrict__ A,
                                              const float* __restrict__ B,
                                              const float* __restrict__ W,
                                              float* __restrict__ C) {
    int col = blockIdx.x * 64 + threadIdx.x;
    int row = blockIdx.y;
    float s = 0.f;
#pragma unroll 8
    for (int k = 0; k < EE; ++k)
        s = fmaf(A[(size_t)row * EE + k] * W[k], B[(size_t)k * NN + col], s);
    C[(size_t)row * NN + col] = s;
}

extern "C" void kernel_launch(void* const* d_in, const int* in_sizes, int n_in,
                              void* d_out, int out_size, void* d_ws, size_t ws_size,
                              hipStream_t stream) {
    const float* A = (const float*)d_in[0];   // DV2_H        [16384,128]
    const float* B = (const float*)d_in[1];   // invDE_HT_DV2 [128,16384]
    const float* W = (const float*)d_in[2];   // W            [128]
    float* C = (float*)d_out;                 // G            [16384,16384] fp32

    const size_t need = (size_t)2 * 4096 * 64 * sizeof(bf16x8);  // 8 MB
    if (ws_size >= need) {
        bf16x8* Apk = (bf16x8*)d_ws;
        bf16x8* Bpk = Apk + (size_t)4096 * 64;
        pack_a<<<1024, 256, 0, stream>>>(A, Apk);
        pack_b<<<1024, 256, 0, stream>>>(B, W, Bpk);
        gemm_pk<<<8192, 512, 0, stream>>>(Apk, Bpk, C);
    } else {
        dim3 g(NN / 64, NN);
        gemm_fb<<<g, 64, 0, stream>>>(A, B, W, C);
    }
}

// Round 12
// 249.274 us; speedup vs baseline: 1.2882x; 1.1260x over previous
//
#include <hip/hip_runtime.h>
#include <hip/hip_bf16.h>

#define NN 16384
#define EE 128

typedef __attribute__((ext_vector_type(8))) short bf16x8;   // 8 bf16 = 4 VGPRs (MFMA A/B frag)
typedef __attribute__((ext_vector_type(4))) float f32x4;    // MFMA C/D frag
typedef __attribute__((ext_vector_type(4))) float f4;

static __device__ inline short f2bf(float f) {
    __hip_bfloat16 h = __float2bfloat16(f);
    return *reinterpret_cast<short*>(&h);
}

// ---------------------------------------------------------------------------
// pack_a: A [16384][128] fp32 -> Apk fragment-packed bf16 (mfma operand layout:
// lane&15 -> index, (lane>>4)*8+j -> k; feedable to either mfma slot).
// ---------------------------------------------------------------------------
__global__ __launch_bounds__(256) void pack_a(const float* __restrict__ A,
                                              bf16x8* __restrict__ out) {
    int lane = threadIdx.x & 63;
    int unit = blockIdx.x * 4 + (threadIdx.x >> 6);   // 0..4095
    int m16 = unit >> 2, ks = unit & 3;
    int row = m16 * 16 + (lane & 15);
    int k0  = ks * 32 + (lane >> 4) * 8;
    const float* src = A + (size_t)row * EE + k0;
    f4 v0 = *reinterpret_cast<const f4*>(src);
    f4 v1 = *reinterpret_cast<const f4*>(src + 4);
    bf16x8 r;
    r[0] = f2bf(v0[0]); r[1] = f2bf(v0[1]); r[2] = f2bf(v0[2]); r[3] = f2bf(v0[3]);
    r[4] = f2bf(v1[0]); r[5] = f2bf(v1[1]); r[6] = f2bf(v1[2]); r[7] = f2bf(v1[3]);
    out[(size_t)unit * 64 + lane] = r;
}

// ---------------------------------------------------------------------------
// pack_b: B [128][16384] fp32, W[128] -> Bpk = bf16(W[k]*B[k][n]), same layout.
// ---------------------------------------------------------------------------
__global__ __launch_bounds__(256) void pack_b(const float* __restrict__ B,
                                              const float* __restrict__ W,
                                              bf16x8* __restrict__ out) {
    int lane = threadIdx.x & 63;
    int unit = blockIdx.x * 4 + (threadIdx.x >> 6);   // 0..4095
    int n16 = unit >> 2, ks = unit & 3;
    int n  = n16 * 16 + (lane & 15);
    int k0 = ks * 32 + (lane >> 4) * 8;
    bf16x8 r;
#pragma unroll
    for (int j = 0; j < 8; ++j) {
        int k = k0 + j;
        r[j] = f2bf(W[k] * B[(size_t)k * NN + n]);
    }
    out[(size_t)unit * 64 + lane] = r;
}

// ---------------------------------------------------------------------------
// gemm_pk: R8 verbatim — measured optimum (248.4 us total). Block tile
// 64x256, 4 waves side-by-side (each 64x64 via swapped-operand mfma).
// Block-cooperative epilogue: per 16-row m-band all 4 waves stage into one
// 16x256 LDS buffer (16 KB, XOR-swizzled, all ds_*_b128), barrier, then
// each wave stores whole 1 KB contiguous rows of C. bm-fast XCD walk.
// Every neighboring design point measured worse: 64B segs (R4), NT (R7),
// bn-fast (R5/R10), 32x256+occ5 (R9), 64x512 2KB rows (R11).
// ---------------------------------------------------------------------------
__global__ __launch_bounds__(256, 4) void gemm_pk(const bf16x8* __restrict__ Apk,
                                                  const bf16x8* __restrict__ Bpk,
                                                  float* __restrict__ C) {
    // XCD chunking, bm-fast. bm in [0,256) (64-row tiles), bn in [0,64)
    // (256-col tiles).
    int bid = blockIdx.x;
    int xcd = bid & 7;
    int r   = bid >> 3;                 // 0..2047
    int bm  = xcd * 32 + (r & 31);      // bm-fast
    int bn  = r >> 5;

    int lane = threadIdx.x & 63;
    int wid  = threadIdx.x >> 6;        // wave 0..3 = column quarter
    int m16_0 = bm * 4;                 // 4 m16-frags (64 rows)
    int n16_0 = bn * 16 + wid * 4;      // 4 n16-frags (64 cols of this wave)

    f32x4 acc[4][4];
#pragma unroll
    for (int m = 0; m < 4; ++m)
#pragma unroll
        for (int n = 0; n < 4; ++n)
            acc[m][n] = (f32x4){0.f, 0.f, 0.f, 0.f};

#pragma unroll
    for (int ks = 0; ks < 4; ++ks) {
        bf16x8 a[4], b[4];
#pragma unroll
        for (int m = 0; m < 4; ++m)
            a[m] = Apk[(size_t)((m16_0 + m) * 4 + ks) * 64 + lane];
#pragma unroll
        for (int n = 0; n < 4; ++n)
            b[n] = Bpk[(size_t)((n16_0 + n) * 4 + ks) * 64 + lane];
#pragma unroll
        for (int m = 0; m < 4; ++m)
#pragma unroll
            for (int n = 0; n < 4; ++n)  // swapped operands (R4-verified math)
                acc[m][n] = __builtin_amdgcn_mfma_f32_16x16x32_bf16(b[n], a[m], acc[m][n], 0, 0, 0);
    }
    // thread owns: C row bm*64 + m*16 + (lane&15),
    //              cols bn*256 + wid*64 + n*16 + (lane>>4)*4 + {0..3}

    // ---- epilogue: block-cooperative 16x256 m-band staging, 1KB row stores --
    __shared__ float sb[16 * 256];               // 16 KB
    int rg  = lane >> 4;                          // 0..3
    int l15 = lane & 15;
    size_t growb = (size_t)bm * 64;
    int    gcolb = bn * 256;

#pragma unroll
    for (int m = 0; m < 4; ++m) {
        // write: wave wid covers cols wid*64 + n*16 + rg*4, rows l15.
        // swizzle (16B-preserving): colf ^= (row&7)<<2  -> uniform banks.
        int swW = (l15 & 7) << 2;
#pragma unroll
        for (int n = 0; n < 4; ++n) {
            int colf = (wid * 64 + n * 16 + rg * 4) ^ swW;
            *reinterpret_cast<f4*>(&sb[l15 * 256 + colf]) = acc[m][n];
        }
        __syncthreads();
        // read+store: wave wid handles rows i*4+wid; 64 lanes x 16B = one
        // full 1 KB contiguous row per instruction.
#pragma unroll
        for (int i = 0; i < 4; ++i) {
            int rl   = i * 4 + wid;
            int colf = (lane * 4) ^ ((rl & 7) << 2);
            f4 v = *reinterpret_cast<const f4*>(&sb[rl * 256 + colf]);
            *reinterpret_cast<f4*>(
                &C[(growb + m * 16 + rl) * NN + gcolb + lane * 4]) = v;
        }
        __syncthreads();   // before next band overwrites sb
    }
}

// ---------------------------------------------------------------------------
// Fallback (only if ws_size < 8 MB): plain fp32, correct but slow.
// ---------------------------------------------------------------------------
__global__ __launch_bounds__(64) void gemm_fb(const float* __restrict__ A,
                                              const float* __restrict__ B,
                                              const float* __restrict__ W,
                                              float* __restrict__ C) {
    int col = blockIdx.x * 64 + threadIdx.x;
    int row = blockIdx.y;
    float s = 0.f;
#pragma unroll 8
    for (int k = 0; k < EE; ++k)
        s = fmaf(A[(size_t)row * EE + k] * W[k], B[(size_t)k * NN + col], s);
    C[(size_t)row * NN + col] = s;
}

extern "C" void kernel_launch(void* const* d_in, const int* in_sizes, int n_in,
                              void* d_out, int out_size, void* d_ws, size_t ws_size,
                              hipStream_t stream) {
    const float* A = (const float*)d_in[0];   // DV2_H        [16384,128]
    const float* B = (const float*)d_in[1];   // invDE_HT_DV2 [128,16384]
    const float* W = (const float*)d_in[2];   // W            [128]
    float* C = (float*)d_out;                 // G            [16384,16384] fp32

    const size_t need = (size_t)2 * 4096 * 64 * sizeof(bf16x8);  // 8 MB
    if (ws_size >= need) {
        bf16x8* Apk = (bf16x8*)d_ws;
        bf16x8* Bpk = Apk + (size_t)4096 * 64;
        pack_a<<<1024, 256, 0, stream>>>(A, Apk);
        pack_b<<<1024, 256, 0, stream>>>(B, W, Bpk);
        gemm_pk<<<16384, 256, 0, stream>>>(Apk, Bpk, C);
    } else {
        dim3 g(NN / 64, NN);
        gemm_fb<<<g, 64, 0, stream>>>(A, B, W, C);
    }
}